// Round 1
// baseline (336.339 us; speedup 1.0000x reference)
//
#include <hip/hip_runtime.h>

// Problem constants (match reference setup_inputs)
#define BB 32
#define TT 1024
#define NN 512
#define CC 3
#define PS 2
#define NBLK (TT / PS)            // 512 patch blocks per batch
#define ROW_FLOATS (NN * CC)      // 1536 floats per (b,t) row
#define ROW_F4 (ROW_FLOATS / 4)   // 384 float4 per row
#define PB_F4 (2 * ROW_F4)        // 768 float4 per patch block (PS=2 rows, contiguous)
#define THREADS 256               // 768 / 256 = exactly 3 iterations per thread

// clang ext_vector so __builtin_nontemporal_store accepts it (HIP float4 is a
// class type, which the builtin rejects).
typedef float vf4 __attribute__((ext_vector_type(4)));

// Merge one float4 of the destination row (a) with the permuted source row (s).
// Flat float index f = 4i+k has channel f%3 == (i+k)%3 (row length 1536 ≡ 0 mod 3,
// patch-block length 3072 ≡ 0 mod 3, so this holds across both rows of the block).
// Take the source component iff its channel is 0.
__device__ __forceinline__ vf4 merge_ch0(vf4 a, vf4 s, int m) {
  vf4 w;
  w.x = (m == 0) ? s.x : a.x;  // channel (i+0)%3
  w.y = (m == 2) ? s.y : a.y;  // channel (i+1)%3
  w.z = (m == 1) ? s.z : a.z;  // channel (i+2)%3
  w.w = (m == 0) ? s.w : a.w;  // channel (i+3)%3
  return w;
}

// One block per (b, j) patch block: both rows t=2j, 2j+1 share one perm entry
// and form one contiguous 12 KiB region. Identity blocks (~75%) are a pure
// streaming copy; permuted blocks read two regions, select channel 0.
// Stores are nontemporal: 'out' is write-once, keep L2/L3 capacity for x so
// the ~25% source-row re-reads hit cache instead of HBM.
__global__ __launch_bounds__(THREADS) void patchperm_kernel(
    const vf4* __restrict__ x,
    const int* __restrict__ perm,
    vf4* __restrict__ out) {
  const int pb = blockIdx.x;          // patch-block index in [0, B*NB)
  const int b = pb >> 9;              // NB == 512
  const int j = pb & (NBLK - 1);
  const int jp = perm[pb];            // perm is [B][NB] contiguous; pb == b*NB+j

  const size_t base = (size_t)(b * TT + (j << 1)) * ROW_F4;
  const vf4* __restrict__ cur = x + base;
  vf4* __restrict__ o = out + base;
  const int tid = threadIdx.x;

  if (jp == j) {
    // Identity block: straight vectorized streaming copy, 3 exact iterations.
#pragma unroll
    for (int it = 0; it < 3; ++it) {
      const int i = tid + THREADS * it;
      vf4 a = cur[i];
      __builtin_nontemporal_store(a, o + i);
    }
  } else {
    const vf4* __restrict__ src = x + (size_t)(b * TT + (jp << 1)) * ROW_F4;
    // Issue all 6 loads up front for maximum memory-level parallelism.
    const vf4 a0 = cur[tid];
    const vf4 a1 = cur[tid + THREADS];
    const vf4 a2 = cur[tid + 2 * THREADS];
    const vf4 s0 = src[tid];
    const vf4 s1 = src[tid + THREADS];
    const vf4 s2 = src[tid + 2 * THREADS];
    // m for iteration it: (tid + it*256) % 3 == (tid + it) % 3  (256 % 3 == 1)
    const int m0 = tid % 3;
    const int m1 = (m0 + 1 == 3) ? 0 : m0 + 1;
    const int m2 = (m1 + 1 == 3) ? 0 : m1 + 1;
    __builtin_nontemporal_store(merge_ch0(a0, s0, m0), o + tid);
    __builtin_nontemporal_store(merge_ch0(a1, s1, m1), o + tid + THREADS);
    __builtin_nontemporal_store(merge_ch0(a2, s2, m2), o + tid + 2 * THREADS);
  }
}

extern "C" void kernel_launch(void* const* d_in, const int* in_sizes, int n_in,
                              void* d_out, int out_size, void* d_ws, size_t ws_size,
                              hipStream_t stream) {
  const vf4* x = (const vf4*)d_in[0];
  const int* perm = (const int*)d_in[1];
  vf4* out = (vf4*)d_out;
  patchperm_kernel<<<BB * NBLK, THREADS, 0, stream>>>(x, perm, out);
}

// Round 2
// 333.459 us; speedup vs baseline: 1.0086x; 1.0086x over previous
//
#include <hip/hip_runtime.h>

// Problem constants (match reference setup_inputs)
#define BB 32
#define TT 1024
#define NN 512
#define CC 3
#define PS 2
#define NBLK (TT / PS)            // 512 patch blocks per batch
#define ROW_FLOATS (NN * CC)      // 1536 floats per (b,t) row
#define ROW_F4 (ROW_FLOATS / 4)   // 384 float4 per row
#define PB_F4 (2 * ROW_F4)        // 768 float4 per patch block (PS=2 rows, contiguous)
#define THREADS 256               // 768 / 256 = exactly 3 iterations per thread

// Merge one float4 of the destination row (a) with the permuted source row (s).
// Flat float index f = 4i+k has channel f%3 == (i+k)%3 (row length 1536 ≡ 0 mod 3,
// patch-block length 3072 ≡ 0 mod 3, so this holds across both rows of the block).
// Take the source component iff its channel is 0.
__device__ __forceinline__ float4 merge_ch0(float4 a, float4 s, int m) {
  float4 w;
  w.x = (m == 0) ? s.x : a.x;  // channel (i+0)%3
  w.y = (m == 2) ? s.y : a.y;  // channel (i+1)%3
  w.z = (m == 1) ? s.z : a.z;  // channel (i+2)%3
  w.w = (m == 0) ? s.w : a.w;  // channel (i+3)%3
  return w;
}

// One block per (b, j) patch block: both rows t=2j, 2j+1 share one perm entry
// and form one contiguous 12 KiB region. Identity blocks (~75%) are a pure
// streaming copy; permuted blocks read two regions, select channel 0.
// NOTE: nontemporal stores measured SLOWER on gfx950 (r1: +14 µs kernel) —
// plain global stores here; the L2/L3 handles the write-once stream fine.
__global__ __launch_bounds__(THREADS) void patchperm_kernel(
    const float4* __restrict__ x,
    const int* __restrict__ perm,
    float4* __restrict__ out) {
  const int pb = blockIdx.x;          // patch-block index in [0, B*NB)
  const int b = pb >> 9;              // NB == 512
  const int j = pb & (NBLK - 1);
  const int jp = perm[pb];            // perm is [B][NB] contiguous; pb == b*NB+j

  const size_t base = (size_t)(b * TT + (j << 1)) * ROW_F4;
  const float4* __restrict__ cur = x + base;
  float4* __restrict__ o = out + base;
  const int tid = threadIdx.x;

  if (jp == j) {
    // Identity block (~75%): straight vectorized copy, 3 exact iterations.
#pragma unroll
    for (int it = 0; it < 3; ++it) {
      const int i = tid + THREADS * it;
      o[i] = cur[i];
    }
  } else {
    const float4* __restrict__ src = x + (size_t)(b * TT + (jp << 1)) * ROW_F4;
    // Issue all 6 loads up front for maximum memory-level parallelism.
    const float4 a0 = cur[tid];
    const float4 a1 = cur[tid + THREADS];
    const float4 a2 = cur[tid + 2 * THREADS];
    const float4 s0 = src[tid];
    const float4 s1 = src[tid + THREADS];
    const float4 s2 = src[tid + 2 * THREADS];
    // m for iteration it: (tid + it*256) % 3 == (tid + it) % 3  (256 % 3 == 1)
    const int m0 = tid % 3;
    const int m1 = (m0 + 1 == 3) ? 0 : m0 + 1;
    const int m2 = (m1 + 1 == 3) ? 0 : m1 + 1;
    o[tid] = merge_ch0(a0, s0, m0);
    o[tid + THREADS] = merge_ch0(a1, s1, m1);
    o[tid + 2 * THREADS] = merge_ch0(a2, s2, m2);
  }
}

extern "C" void kernel_launch(void* const* d_in, const int* in_sizes, int n_in,
                              void* d_out, int out_size, void* d_ws, size_t ws_size,
                              hipStream_t stream) {
  const float4* x = (const float4*)d_in[0];
  const int* perm = (const int*)d_in[1];
  float4* out = (float4*)d_out;
  patchperm_kernel<<<BB * NBLK, THREADS, 0, stream>>>(x, perm, out);
}

// Round 3
// 326.568 us; speedup vs baseline: 1.0299x; 1.0211x over previous
//
#include <hip/hip_runtime.h>

// Problem constants (match reference setup_inputs)
#define BB 32
#define TT 1024
#define NN 512
#define CC 3
#define PS 2
#define NBLK (TT / PS)            // 512
#define ROW_FLOATS (NN * CC)      // 1536 floats per (b,t) row
#define ROW_F4 (ROW_FLOATS / 4)   // 384 float4 per row (6144 B, 16B-aligned)

// One block per (b, t) row. Row copy is fully coalesced float4.
// Channel-0 gather: component k of float4 i is flat offset 4i+k, whose
// channel is (4i+k) % 3 == (i+k) % 3. It comes from the permuted source row
// iff that channel is 0.
// NOTE (session journal): r1 tried patch-block granularity + nontemporal
// stores (336.3 µs), r2 patch-block + plain stores (333.5 µs) — both measured
// worse than or equal to this row-based version (326.1 µs) within fill-noise.
// Nontemporal stores are a measured ~3 µs regression on gfx950 here.
__global__ __launch_bounds__(256) void patchperm_kernel(
    const float4* __restrict__ x,
    const int* __restrict__ perm,
    float4* __restrict__ out) {
  const int r = blockIdx.x;          // row index in [0, B*T)
  const int b = r >> 10;             // T == 1024
  const int t = r & (TT - 1);
  const int j = t >> 1;              // PS == 2
  const int jp = perm[b * NBLK + j];
  const int tsrc = (jp << 1) | (t & 1);

  const size_t rowbase = (size_t)r * ROW_F4;
  const float4* __restrict__ cur = x + rowbase;
  float4* __restrict__ o = out + rowbase;

  if (tsrc == t) {
    // Identity block (~75% of rows): straight vectorized copy.
    for (int i = threadIdx.x; i < ROW_F4; i += 256) {
      o[i] = cur[i];
    }
  } else {
    const float4* __restrict__ src =
        x + ((size_t)(b * TT + tsrc)) * ROW_F4;
    for (int i = threadIdx.x; i < ROW_F4; i += 256) {
      const float4 a = cur[i];
      const float4 s = src[i];
      const int m = i % 3;
      float4 w;
      w.x = (m == 0) ? s.x : a.x;  // channel (i+0)%3
      w.y = (m == 2) ? s.y : a.y;  // channel (i+1)%3
      w.z = (m == 1) ? s.z : a.z;  // channel (i+2)%3
      w.w = (m == 0) ? s.w : a.w;  // channel (i+3)%3
      o[i] = w;
    }
  }
}

extern "C" void kernel_launch(void* const* d_in, const int* in_sizes, int n_in,
                              void* d_out, int out_size, void* d_ws, size_t ws_size,
                              hipStream_t stream) {
  const float4* x = (const float4*)d_in[0];
  const int* perm = (const int*)d_in[1];
  float4* out = (float4*)d_out;
  patchperm_kernel<<<BB * TT, 256, 0, stream>>>(x, perm, out);
}